// Round 7
// baseline (1089.297 us; speedup 1.0000x reference)
//
#include <hip/hip_runtime.h>

// ChebConv GNN: 6 layers x (K=5 Chebyshev), 50000 nodes / 640000 edges, WIDTH=128.
//  - CSR packed to 4B/edge: {src:20 | exp4 | mant8} (norm = -m*2^(e-112)).
//  - All Chebyshev T_k stored bf16; fp32 accumulate.
//  - R20: prop is XCD-CHANNEL-PARTITIONED. rocprof (R6, replay-serialized prop):
//    FETCH_SIZE=72MB/prop vs ~28MB ideal -> the 12.8MB gather table misses the
//    4MB/XCD L2 (~31% resident). Quarter q=(blockIdx%8)>>1 handles channels
//    [32q,32q+32) for ALL nodes (4 lanes/node, uint4): per-XCD-pair working set
//    3.2MB < 4MB L2 -> L2-resident gathers. Wave still gathers 1KB/instr
//    (16 groups x 64B); FMA + per-edge decode identical; csr re-read 4x (L3-hot).
//    Correctness independent of block->XCD mapping (any mapping is correct).
//  - R15-17: degree-sorting NEUTRAL (3-round A/B) -> props not divergence-bound.
//  - R17 lesson: never co-locate a latency-bound gather phase with an LDS-heavy
//    MFMA phase in one block (45KB LDS fusion: Occ 18%, 72us/dispatch).
//  - R18: GEMM tile 128x128, 512 thr, 8 waves, LDS 36.9KB (838.6us total).
//  - FINAL LAYER (R14): y = sum_k T_k(L) (H (W_k w_lin)) + const; 5-wide fp32
//    recurrence (prop_small) replaces 4 full props + full GEMM.
//  NOTE (R9): __builtin_nontemporal_* scalarizes vector accesses on gfx950 - avoid.
//  NOTE (R12/13): cooperative launch no-ops; software grid barriers cost 10x.

#define NN 50000
#define NE 640000
#define WID 128
#define PROP_BLOCKS 2048

typedef __attribute__((ext_vector_type(8))) short bf16x8;
typedef __attribute__((ext_vector_type(4))) float f32x4;

__device__ __forceinline__ unsigned short f2bf(float f) {
  union { float f; unsigned int u; } v; v.f = f;
  unsigned int r = v.u + 0x7FFF + ((v.u >> 16) & 1);  // RNE
  return (unsigned short)(r >> 16);
}
__device__ __forceinline__ unsigned int pack2(float lo, float hi) {
  return (unsigned int)f2bf(lo) | ((unsigned int)f2bf(hi) << 16);
}
__device__ __forceinline__ float bflo(unsigned int u) {
  return __uint_as_float(u << 16);
}
__device__ __forceinline__ float bfhi(unsigned int u) {
  return __uint_as_float(u & 0xffff0000u);
}
// decode packed edge: bits 11..8 = exp-112, 7..0 = mant (norm is negative)
__device__ __forceinline__ float dec_norm(unsigned int p) {
  unsigned int lo = p & 0xfffu;
  float v = -__uint_as_float(((112u + ((p >> 8) & 15u)) << 23) | ((p & 255u) << 15));
  return (lo == 0u) ? 0.f : v;
}

// ---------------- preprocessing ----------------

__global__ __launch_bounds__(256) void degree_kernel(const int* __restrict__ ei,
                                                     int* __restrict__ deg, int E) {
  int e = blockIdx.x * 256 + threadIdx.x;
  if (e < E) atomicAdd(&deg[ei[E + e]], 1);
}

__global__ __launch_bounds__(256) void scan1_kernel(const int* __restrict__ deg,
                                                    int* __restrict__ lex,
                                                    int* __restrict__ bsum,
                                                    float* __restrict__ dinv, int n) {
  __shared__ int ws[4];
  int tid = threadIdx.x, lane = tid & 63, w = tid >> 6;
  int i = blockIdx.x * 256 + tid;
  int cnt = (i < n) ? deg[i] : 0;
  if (i < n) {
    float d = (float)cnt;
    dinv[i] = d > 0.0f ? rsqrtf(d) : 0.0f;
  }
  int v = cnt;
#pragma unroll
  for (int off = 1; off < 64; off <<= 1) {
    int u = __shfl_up(v, off, 64);
    if (lane >= off) v += u;
  }
  if (lane == 63) ws[w] = v;
  __syncthreads();
  int wexcl = 0;
#pragma unroll
  for (int k = 0; k < 4; ++k) wexcl += (k < w) ? ws[k] : 0;
  if (i < n) lex[i] = wexcl + v - cnt;
  if (tid == 255) bsum[blockIdx.x] = wexcl + v;
}

__global__ __launch_bounds__(256) void scan2_kernel(const int* __restrict__ bsum,
                                                    int* __restrict__ boff,
                                                    int* __restrict__ row_end, int nb) {
  __shared__ int ws[4];
  int tid = threadIdx.x, lane = tid & 63, w = tid >> 6;
  int cnt = (tid < nb) ? bsum[tid] : 0;
  int v = cnt;
#pragma unroll
  for (int off = 1; off < 64; off <<= 1) {
    int u = __shfl_up(v, off, 64);
    if (lane >= off) v += u;
  }
  if (lane == 63) ws[w] = v;
  __syncthreads();
  int wexcl = 0;
#pragma unroll
  for (int k = 0; k < 4; ++k) wexcl += (k < w) ? ws[k] : 0;
  if (tid < nb) boff[tid] = wexcl + v - cnt;
  if (tid == 255) *row_end = wexcl + v;
}

__global__ __launch_bounds__(256) void scan3_kernel(const int* __restrict__ lex,
                                                    const int* __restrict__ boff,
                                                    int* __restrict__ row_start,
                                                    int* __restrict__ fill_ptr, int n) {
  int i = blockIdx.x * 256 + threadIdx.x;
  if (i < n) {
    int rs = lex[i] + boff[blockIdx.x];
    row_start[i] = rs;
    fill_ptr[i] = rs;
  }
}

__global__ __launch_bounds__(256) void fill_kernel(const int* __restrict__ ei,
                                                   const float* __restrict__ dinv,
                                                   int* __restrict__ fill_ptr,
                                                   unsigned int* __restrict__ csr, int E) {
  int e = blockIdx.x * 256 + threadIdx.x;
  if (e < E) {
    int s = ei[e];
    int d = ei[E + e];
    int pos = atomicAdd(&fill_ptr[d], 1);
    float mag = dinv[s] * dinv[d];
    unsigned int bits = __float_as_uint(mag);
    unsigned int pk = (unsigned int)s << 12;
    if (bits != 0u) {
      bits += 0x4000u;  // round at bit 15 (carry propagates into exponent)
      int ex = (int)((bits >> 23) & 255u) - 112;
      ex = max(0, min(15, ex));
      pk |= ((unsigned int)ex << 8) | ((bits >> 15) & 0xffu);
    }
    csr[pos] = pk;
  }
}

// merged: x fp32 -> bf16 (first nx elems) and conv_w transpose -> Wt bf16 (next nw)
// nw covers layers 0..4 only; layer 5's weights go through vk_kernel instead.
__global__ __launch_bounds__(256) void cvt_kernel(const float* __restrict__ x,
                                                  unsigned short* __restrict__ xo,
                                                  const float* __restrict__ w,
                                                  unsigned short* __restrict__ wt,
                                                  int nx, int nw) {
  int i = blockIdx.x * 256 + threadIdx.x;
  if (i < nx) {
    xo[i] = f2bf(x[i]);
  } else if (i < nx + nw) {
    int j = i - nx;
    int l = j / (WID * 640);
    int r = j % (WID * 640);
    int col = r / 640;
    int k = r % 640;
    int kk = k >> 7, m = k & 127;
    wt[j] = f2bf(w[(((size_t)l * 5 + kk) * WID + m) * WID + col]);
  }
}

// final-layer weight collapse: V[k][i] = sum_j conv_w[5][k][i][j] * lin_w[j]
// cst = sum_c conv_b[5][c]*lin_w[c] + lin_b.  3 blocks, one dot per thread.
__global__ __launch_bounds__(256) void vk_kernel(const float* __restrict__ w,
                                                 const float* __restrict__ b,
                                                 const float* __restrict__ lw,
                                                 const float* __restrict__ lb,
                                                 float* __restrict__ V,
                                                 float* __restrict__ cst) {
  int idx = blockIdx.x * 256 + threadIdx.x;
  if (idx < 5 * WID) {
    int k = idx / WID, i = idx % WID;
    const float4* wr = (const float4*)(w + (((size_t)5 * 5 + k) * WID + i) * WID);
    const float4* l4 = (const float4*)lw;
    float s = 0.f;
#pragma unroll 8
    for (int j = 0; j < WID / 4; ++j) {
      float4 a = wr[j], c = l4[j];
      s += a.x * c.x + a.y * c.y + a.z * c.z + a.w * c.w;
    }
    V[idx] = s;
  }
  if (blockIdx.x == 0 && threadIdx.x == 0) {
    float s = 0.f;
    for (int c = 0; c < WID; ++c) s += b[5 * WID + c] * lw[c];
    *cst = s + lb[0];
  }
}

// ---------------- propagate: out(bf16) = scale * (L_hat @ xin(bf16)) - sub(bf16) ----------
// R20: XCD-channel-partitioned. Quarter q = (blockIdx%8)>>1 handles channels
// [32q, 32q+32) for ALL nodes. 4 lanes/node (16B = 8ch per lane), 64 node-slots
// per 256-thr block, 512 blocks per quarter, grid-stride. Gather working set per
// XCD pair = N*64B = 3.2MB -> L2-resident.

__global__ __launch_bounds__(256) void prop_kernel(unsigned short* __restrict__ out,
                                                   const unsigned short* __restrict__ xin,
                                                   const unsigned short* __restrict__ sub,
                                                   float scale,
                                                   const int* __restrict__ row_start,
                                                   const unsigned int* __restrict__ csr,
                                                   int n) {
  int t = threadIdx.x & 3;          // lane within 4-lane node group
  int slot = threadIdx.x >> 2;      // 0..63 node slots
  int xcd = blockIdx.x & 7;
  int q = xcd >> 1;                 // channel quarter 0..3
  int r = ((blockIdx.x >> 3) << 1) | (xcd & 1);  // rank within quarter 0..511
  int co = q * 32 + t * 8;          // this lane's channel offset

  for (int node = r * 64 + slot; node < n; node += 512 * 64) {
    int s = row_start[node], e = row_start[node + 1];
    float a0 = 0.f, a1 = 0.f, a2 = 0.f, a3 = 0.f;
    float a4 = 0.f, a5 = 0.f, a6 = 0.f, a7 = 0.f;
    for (int base = s; base < e; base += 4) {
      int cnt = min(4, e - base);
      unsigned int ed = (t < cnt) ? csr[base + t] : 0u;
      if (cnt == 4) {
        unsigned int p0 = (unsigned int)__shfl((int)ed, 0, 4);
        unsigned int p1 = (unsigned int)__shfl((int)ed, 1, 4);
        unsigned int p2 = (unsigned int)__shfl((int)ed, 2, 4);
        unsigned int p3 = (unsigned int)__shfl((int)ed, 3, 4);
        int s0 = p0 >> 12, s1 = p1 >> 12, s2 = p2 >> 12, s3 = p3 >> 12;
        float n0 = dec_norm(p0), n1 = dec_norm(p1), n2 = dec_norm(p2), n3 = dec_norm(p3);
        const uint4 v0 = *(const uint4*)(xin + (size_t)s0 * WID + co);
        const uint4 v1 = *(const uint4*)(xin + (size_t)s1 * WID + co);
        const uint4 v2 = *(const uint4*)(xin + (size_t)s2 * WID + co);
        const uint4 v3 = *(const uint4*)(xin + (size_t)s3 * WID + co);
        a0 += n0 * bflo(v0.x) + n1 * bflo(v1.x) + n2 * bflo(v2.x) + n3 * bflo(v3.x);
        a1 += n0 * bfhi(v0.x) + n1 * bfhi(v1.x) + n2 * bfhi(v2.x) + n3 * bfhi(v3.x);
        a2 += n0 * bflo(v0.y) + n1 * bflo(v1.y) + n2 * bflo(v2.y) + n3 * bflo(v3.y);
        a3 += n0 * bfhi(v0.y) + n1 * bfhi(v1.y) + n2 * bfhi(v2.y) + n3 * bfhi(v3.y);
        a4 += n0 * bflo(v0.z) + n1 * bflo(v1.z) + n2 * bflo(v2.z) + n3 * bflo(v3.z);
        a5 += n0 * bfhi(v0.z) + n1 * bfhi(v1.z) + n2 * bfhi(v2.z) + n3 * bfhi(v3.z);
        a6 += n0 * bflo(v0.w) + n1 * bflo(v1.w) + n2 * bflo(v2.w) + n3 * bflo(v3.w);
        a7 += n0 * bfhi(v0.w) + n1 * bfhi(v1.w) + n2 * bfhi(v2.w) + n3 * bfhi(v3.w);
      } else {
        for (int j = 0; j < cnt; ++j) {
          unsigned int pj = (unsigned int)__shfl((int)ed, j, 4);
          int sj = pj >> 12;
          float nj = dec_norm(pj);
          const uint4 v = *(const uint4*)(xin + (size_t)sj * WID + co);
          a0 += nj * bflo(v.x); a1 += nj * bfhi(v.x);
          a2 += nj * bflo(v.y); a3 += nj * bfhi(v.y);
          a4 += nj * bflo(v.z); a5 += nj * bfhi(v.z);
          a6 += nj * bflo(v.w); a7 += nj * bfhi(v.w);
        }
      }
    }
    size_t o = (size_t)node * WID + co;
    float r0 = scale * a0, r1 = scale * a1, r2 = scale * a2, r3 = scale * a3;
    float r4 = scale * a4, r5 = scale * a5, r6 = scale * a6, r7 = scale * a7;
    if (sub) {
      const uint4 sv = *(const uint4*)(sub + o);
      r0 -= bflo(sv.x); r1 -= bfhi(sv.x);
      r2 -= bflo(sv.y); r3 -= bfhi(sv.y);
      r4 -= bflo(sv.z); r5 -= bfhi(sv.z);
      r6 -= bflo(sv.w); r7 -= bfhi(sv.w);
    }
    uint4 wv;
    wv.x = pack2(r0, r1); wv.y = pack2(r2, r3);
    wv.z = pack2(r4, r5); wv.w = pack2(r6, r7);
    *(uint4*)(out + o) = wv;
  }
}

// ---------------- final layer: skinny fp32 path ----------------
// U[n][0..4] = H[n][:] @ v_k ; U[n][5..7]=0 ; y[n] = U[n][0] + cst
__global__ __launch_bounds__(256) void final_proj(const unsigned short* __restrict__ H,
                                                  const float* __restrict__ V,
                                                  const float* __restrict__ cstp,
                                                  float* __restrict__ U,
                                                  float* __restrict__ y, int n) {
  int t = threadIdx.x & 15;
  int node = blockIdx.x * 16 + (threadIdx.x >> 4);
  if (node >= n) return;
  const uint4 h = *(const uint4*)(H + (size_t)node * WID + t * 8);
  float hv0 = bflo(h.x), hv1 = bfhi(h.x), hv2 = bflo(h.y), hv3 = bfhi(h.y);
  float hv4 = bflo(h.z), hv5 = bfhi(h.z), hv6 = bflo(h.w), hv7 = bfhi(h.w);
  float p[5];
#pragma unroll
  for (int k = 0; k < 5; ++k) {
    const float4* vp = (const float4*)(V + k * WID + t * 8);
    float4 v0 = vp[0], v1 = vp[1];
    float s = hv0 * v0.x + hv1 * v0.y + hv2 * v0.z + hv3 * v0.w +
              hv4 * v1.x + hv5 * v1.y + hv6 * v1.z + hv7 * v1.w;
#pragma unroll
    for (int off = 1; off < 16; off <<= 1) s += __shfl_xor(s, off, 16);
    p[k] = s;
  }
  if (t == 0) {
    float4 u0 = {p[0], p[1], p[2], p[3]};
    float4 u1 = {p[4], 0.f, 0.f, 0.f};
    *(float4*)(U + (size_t)node * 8) = u0;
    *(float4*)(U + (size_t)node * 8 + 4) = u1;
    y[node] = p[0] + *cstp;
  }
}

// 8-wide fp32 prop: out[n][:] = scale*(L_hat @ xin)[n][:] - sub[n][:]
// y[n] += out[n][pick].  Table is N*32B = 1.6MB -> L2-resident gathers.
__global__ __launch_bounds__(256) void prop_small(float* __restrict__ out,
                                                  const float* __restrict__ xin,
                                                  const float* __restrict__ sub,
                                                  float scale, int pick,
                                                  float* __restrict__ y,
                                                  const int* __restrict__ row_start,
                                                  const unsigned int* __restrict__ csr,
                                                  int n) {
  int node = blockIdx.x * 256 + threadIdx.x;
  if (node >= n) return;
  int s = row_start[node], e = row_start[node + 1];
  float a0 = 0.f, a1 = 0.f, a2 = 0.f, a3 = 0.f;
  float a4 = 0.f, a5 = 0.f, a6 = 0.f, a7 = 0.f;
  for (int i = s; i < e; ++i) {
    unsigned int p = csr[i];
    int src = (int)(p >> 12);
    float nv = dec_norm(p);
    const float4* r = (const float4*)(xin + (size_t)src * 8);
    float4 v0 = r[0], v1 = r[1];
    a0 += nv * v0.x; a1 += nv * v0.y; a2 += nv * v0.z; a3 += nv * v0.w;
    a4 += nv * v1.x; a5 += nv * v1.y; a6 += nv * v1.z; a7 += nv * v1.w;
  }
  float o0 = scale * a0, o1 = scale * a1, o2 = scale * a2, o3 = scale * a3;
  float o4 = scale * a4, o5 = scale * a5, o6 = scale * a6, o7 = scale * a7;
  if (sub) {
    const float4* sv = (const float4*)(sub + (size_t)node * 8);
    float4 s0 = sv[0], s1 = sv[1];
    o0 -= s0.x; o1 -= s0.y; o2 -= s0.z; o3 -= s0.w;
    o4 -= s1.x; o5 -= s1.y; o6 -= s1.z; o7 -= s1.w;
  }
  float4 w0 = {o0, o1, o2, o3};
  float4 w1 = {o4, o5, o6, o7};
  *(float4*)(out + (size_t)node * 8) = w0;
  *(float4*)(out + (size_t)node * 8 + 4) = w1;
  // static select (avoid runtime-indexed array -> scratch, rule #20)
  float yp = o1;
  if (pick == 2) yp = o2;
  if (pick == 3) yp = o3;
  if (pick == 4) yp = o4;
  y[node] += yp;
}

// ---------------- fused layer GEMM: H[N,128] = A[N,640](bf16) @ W[640,128] + b ----------
// R18: 512 thr = 8 waves; block tile 128 rows x 128 cols (wave w: rows w*16..w*16+15).
// BK=64, 10 k-chunks, LDS As[128][72] + Bs[128][72] (36.9 KB -> 4 blocks/CU max).
// Register prefetch of chunk kc+1 issued after barrier1; 16 MFMAs/wave per stage
// hide it. ReLU epilogue, bf16 out.

__global__ __launch_bounds__(512) void cheb_gemm(
    const unsigned short* __restrict__ T0, const unsigned short* __restrict__ T1,
    const unsigned short* __restrict__ T2, const unsigned short* __restrict__ T3,
    const unsigned short* __restrict__ T4,
    const unsigned short* __restrict__ Wt,
    const float* __restrict__ bias,
    unsigned short* __restrict__ Hb, int M) {
  __shared__ unsigned short As[128][72];  // [row][k 0..63], pad to 72
  __shared__ unsigned short Bs[128][72];  // [col][k 0..63]
  const unsigned short* chunks[5] = {T0, T1, T2, T3, T4};
  int tid = threadIdx.x;
  int wave = tid >> 6, lane = tid & 63;
  int lrow = lane & 15, quad = lane >> 4;
  int rowBase = blockIdx.x * 128;

  f32x4 acc[8];
#pragma unroll
  for (int b = 0; b < 8; ++b) acc[b] = (f32x4){0.f, 0.f, 0.f, 0.f};

  // staging coords: A rows 0..127 (4 thr/row), B cols 0..127 (4 thr/col);
  // each thread stages 2x int4 (16 shorts) for A and for B.
  int ar = tid >> 2, aseg = (tid & 3) * 16;
  int agrow = min(rowBase + ar, M - 1);  // clamp (garbage rows never stored)
  int bc = tid >> 2, bseg = (tid & 3) * 16;

  int4 aR0, aR1, bR0, bR1;
  {
    const unsigned short* ap = chunks[0] + (size_t)agrow * WID + aseg;
    aR0 = *(const int4*)ap;
    aR1 = *(const int4*)(ap + 8);
    const unsigned short* bp = Wt + (size_t)bc * 640 + bseg;
    bR0 = *(const int4*)bp;
    bR1 = *(const int4*)(bp + 8);
  }

  for (int kc = 0; kc < 10; ++kc) {
    *(int4*)(&As[ar][aseg]) = aR0;
    *(int4*)(&As[ar][aseg + 8]) = aR1;
    *(int4*)(&Bs[bc][bseg]) = bR0;
    *(int4*)(&Bs[bc][bseg + 8]) = bR1;
    __syncthreads();

    if (kc < 9) {  // prefetch next chunk; overlaps the 16 MFMAs below
      int kn = kc + 1;
      const unsigned short* ap =
          chunks[kn >> 1] + (size_t)agrow * WID + (kn & 1) * 64 + aseg;
      aR0 = *(const int4*)ap;
      aR1 = *(const int4*)(ap + 8);
      const unsigned short* bp = Wt + (size_t)bc * 640 + kn * 64 + bseg;
      bR0 = *(const int4*)bp;
      bR1 = *(const int4*)(bp + 8);
    }

    bf16x8 a0 = *(bf16x8*)(&As[wave * 16 + lrow][quad * 8]);
    bf16x8 a1 = *(bf16x8*)(&As[wave * 16 + lrow][32 + quad * 8]);
#pragma unroll
    for (int ct = 0; ct < 8; ++ct) {
      bf16x8 b0 = *(bf16x8*)(&Bs[ct * 16 + lrow][quad * 8]);
      acc[ct] = __builtin_amdgcn_mfma_f32_16x16x32_bf16(a0, b0, acc[ct], 0, 0, 0);
      bf16x8 b1 = *(bf16x8*)(&Bs[ct * 16 + lrow][32 + quad * 8]);
      acc[ct] = __builtin_amdgcn_mfma_f32_16x16x32_bf16(a1, b1, acc[ct], 0, 0, 0);
    }
    __syncthreads();
  }

  // epilogue: C/D layout col=lane&15, row=quad*4+reg ; wave rows rowBase+wave*16+...
#pragma unroll
  for (int ct = 0; ct < 8; ++ct) {
    int gcol = ct * 16 + lrow;
    float bv = bias[gcol];
#pragma unroll
    for (int reg = 0; reg < 4; ++reg) {
      int grow = rowBase + wave * 16 + quad * 4 + reg;
      if (grow < M) {
        float v = fmaxf(acc[ct][reg] + bv, 0.f);
        Hb[(size_t)grow * WID + gcol] = f2bf(v);
      }
    }
  }
}

// ---------------- host orchestration ----------------

extern "C" void kernel_launch(void* const* d_in, const int* in_sizes, int n_in,
                              void* d_out, int out_size, void* d_ws, size_t ws_size,
                              hipStream_t stream) {
  const float* x = (const float*)d_in[0];
  const int* ei = (const int*)d_in[1];          // int32 per harness contract
  const float* conv_w = (const float*)d_in[2];  // [6][5][128][128]
  const float* conv_b = (const float*)d_in[3];  // [6][128]
  const float* lin_w = (const float*)d_in[4];   // [128]
  const float* lin_b = (const float*)d_in[5];   // [1]

  const int N = NN, E = NE, C = WID, L = 6;
  const int NB = (N + 255) / 256;

  char* ws = (char*)d_ws;
  size_t off = 0;
  auto alloc = [&](size_t bytes) -> void* {
    void* p = ws + off;
    off = (off + bytes + 255) & ~(size_t)255;
    return p;
  };
  int* deg = (int*)alloc((size_t)N * 4);
  float* dinv = (float*)alloc((size_t)N * 4);
  int* row_start = (int*)alloc((size_t)(N + 1) * 4);
  int* fill_ptr = (int*)alloc((size_t)N * 4);
  int* lex = (int*)alloc((size_t)N * 4);
  int* bsum = (int*)alloc((size_t)NB * 4);
  int* boff = (int*)alloc((size_t)NB * 4);
  unsigned int* csr = (unsigned int*)alloc((size_t)E * 4);
  unsigned short* Xbf = (unsigned short*)alloc((size_t)N * C * 2);
  unsigned short* Hb0 = (unsigned short*)alloc((size_t)N * C * 2);
  unsigned short* Hb1 = (unsigned short*)alloc((size_t)N * C * 2);
  unsigned short* T1b = (unsigned short*)alloc((size_t)N * C * 2);
  unsigned short* T2b = (unsigned short*)alloc((size_t)N * C * 2);
  unsigned short* T3b = (unsigned short*)alloc((size_t)N * C * 2);
  unsigned short* T4b = (unsigned short*)alloc((size_t)N * C * 2);
  unsigned short* Wt = (unsigned short*)alloc((size_t)5 * C * 640 * 2);
  float* V = (float*)alloc((size_t)5 * C * 4);
  float* cst = (float*)alloc(4);

  // preprocessing
  hipMemsetAsync(deg, 0, (size_t)N * 4, stream);
  degree_kernel<<<(E + 255) / 256, 256, 0, stream>>>(ei, deg, E);
  scan1_kernel<<<NB, 256, 0, stream>>>(deg, lex, bsum, dinv, N);
  scan2_kernel<<<1, 256, 0, stream>>>(bsum, boff, &row_start[N], NB);
  scan3_kernel<<<NB, 256, 0, stream>>>(lex, boff, row_start, fill_ptr, N);
  fill_kernel<<<(E + 255) / 256, 256, 0, stream>>>(ei, dinv, fill_ptr, csr, E);
  {
    int nx = N * C, nw = 5 * C * 640;  // layer-5 weights collapse via vk_kernel
    cvt_kernel<<<(nx + nw + 255) / 256, 256, 0, stream>>>(x, Xbf, conv_w, Wt, nx, nw);
  }
  vk_kernel<<<3, 256, 0, stream>>>(conv_w, conv_b, lin_w, lin_b, V, cst);

  const int gg = (N + 127) / 128;  // gemm grid (128 rows/block)

  // layers 0..4: full-width props + MFMA GEMM + ReLU
  for (int l = 0; l < 5; ++l) {
    const unsigned short* T0 = (l == 0) ? Xbf : ((l & 1) ? Hb0 : Hb1);
    unsigned short* Hb = (l & 1) ? Hb1 : Hb0;

    prop_kernel<<<PROP_BLOCKS, 256, 0, stream>>>(T1b, T0, nullptr, 1.0f, row_start, csr, N);
    prop_kernel<<<PROP_BLOCKS, 256, 0, stream>>>(T2b, T1b, T0, 2.0f, row_start, csr, N);
    prop_kernel<<<PROP_BLOCKS, 256, 0, stream>>>(T3b, T2b, T1b, 2.0f, row_start, csr, N);
    prop_kernel<<<PROP_BLOCKS, 256, 0, stream>>>(T4b, T3b, T2b, 2.0f, row_start, csr, N);
    cheb_gemm<<<gg, 512, 0, stream>>>(T0, T1b, T2b, T3b, T4b,
                                      Wt + (size_t)l * C * 640, conv_b + (size_t)l * C,
                                      Hb, N);
  }

  // final layer (l=5): y = sum_k T_k(L) (H v_k) + cst -- 5-wide fp32 recurrence.
  // H = Hb0 (layer 4 output). Reuse T-buffers as fp32 [N][8] (1.6MB each).
  {
    float* y = (float*)d_out;
    float* U  = (float*)T1b;
    float* P1 = (float*)T2b;
    float* P2 = (float*)T3b;
    float* P3 = (float*)T4b;
    float* P4 = (float*)Xbf;
    const int pg = (N + 255) / 256;
    final_proj<<<(N + 15) / 16, 256, 0, stream>>>(Hb0, V, cst, U, y, N);
    prop_small<<<pg, 256, 0, stream>>>(P1, U, nullptr, 1.0f, 1, y, row_start, csr, N);
    prop_small<<<pg, 256, 0, stream>>>(P2, P1, U, 2.0f, 2, y, row_start, csr, N);
    prop_small<<<pg, 256, 0, stream>>>(P3, P2, P1, 2.0f, 3, y, row_start, csr, N);
    prop_small<<<pg, 256, 0, stream>>>(P4, P3, P2, 2.0f, 4, y, row_start, csr, N);
  }
}

// Round 8
// 881.858 us; speedup vs baseline: 1.2352x; 1.2352x over previous
//
#include <hip/hip_runtime.h>

// ChebConv GNN: 6 layers x (K=5 Chebyshev), 50000 nodes / 640000 edges, WIDTH=128.
//  - CSR packed to 4B/edge: {src:20 | exp4 | mant8} (norm = -m*2^(e-112)).
//  - All Chebyshev T_k stored bf16 in SLAB LAYOUT (R21): 4 slabs of [N][32ch]
//    (3.2MB each). Slab q holds channels [32q,32q+32) for all nodes.
//  - R20 (FAILED): quarter-partition on interleaved layout: quarter q's 64B read
//    split 128B cache lines with quarter q^1 (other XCD) -> FETCH 72->110MB,
//    prop 27->40us. R21 fixes it: slab layout means a line = 2 nodes of the SAME
//    slab -> no split waste; 3.2MB slab < 4MB XCD L2 -> L2-resident gathers.
//    Edge-order arithmetic bitwise identical to R6 (same 4-edge grouping).
//  - prop: quarter q=(blockIdx&7)>>1 (XCD round-robin), 4 lanes/node, 64 slots/blk,
//    512 blocks/quarter grid-stride; uint4 gathers, shfl-broadcast descriptors.
//  - R15-17: degree-sorting NEUTRAL (3-round A/B) -> props not divergence-bound.
//  - R17 lesson: never co-locate a latency-bound gather phase with an LDS-heavy
//    MFMA phase in one block (45KB LDS fusion: Occ 18%, 72us/dispatch).
//  - R18: GEMM tile 128x128, 512 thr, 8 waves, LDS 36.9KB (838.6us total).
//  - FINAL LAYER (R14): y = sum_k T_k(L) (H (W_k w_lin)) + const; 5-wide fp32
//    recurrence (prop_small) replaces 4 full props + full GEMM.
//  NOTE (R9): __builtin_nontemporal_* scalarizes vector accesses on gfx950 - avoid.
//  NOTE (R12/13): cooperative launch no-ops; software grid barriers cost 10x.

#define NN 50000
#define NE 640000
#define WID 128
#define PROP_BLOCKS 2048

typedef __attribute__((ext_vector_type(8))) short bf16x8;
typedef __attribute__((ext_vector_type(4))) float f32x4;

__device__ __forceinline__ unsigned short f2bf(float f) {
  union { float f; unsigned int u; } v; v.f = f;
  unsigned int r = v.u + 0x7FFF + ((v.u >> 16) & 1);  // RNE
  return (unsigned short)(r >> 16);
}
__device__ __forceinline__ unsigned int pack2(float lo, float hi) {
  return (unsigned int)f2bf(lo) | ((unsigned int)f2bf(hi) << 16);
}
__device__ __forceinline__ float bflo(unsigned int u) {
  return __uint_as_float(u << 16);
}
__device__ __forceinline__ float bfhi(unsigned int u) {
  return __uint_as_float(u & 0xffff0000u);
}
// decode packed edge: bits 11..8 = exp-112, 7..0 = mant (norm is negative)
__device__ __forceinline__ float dec_norm(unsigned int p) {
  unsigned int lo = p & 0xfffu;
  float v = -__uint_as_float(((112u + ((p >> 8) & 15u)) << 23) | ((p & 255u) << 15));
  return (lo == 0u) ? 0.f : v;
}
// slab address of channel c, node nd inside a [4][N][32] bf16 buffer
__device__ __forceinline__ size_t slab_off(int c, int nd) {
  return ((size_t)(c >> 5) * NN + nd) * 32 + (c & 31);
}

// ---------------- preprocessing ----------------

__global__ __launch_bounds__(256) void degree_kernel(const int* __restrict__ ei,
                                                     int* __restrict__ deg, int E) {
  int e = blockIdx.x * 256 + threadIdx.x;
  if (e < E) atomicAdd(&deg[ei[E + e]], 1);
}

__global__ __launch_bounds__(256) void scan1_kernel(const int* __restrict__ deg,
                                                    int* __restrict__ lex,
                                                    int* __restrict__ bsum,
                                                    float* __restrict__ dinv, int n) {
  __shared__ int ws[4];
  int tid = threadIdx.x, lane = tid & 63, w = tid >> 6;
  int i = blockIdx.x * 256 + tid;
  int cnt = (i < n) ? deg[i] : 0;
  if (i < n) {
    float d = (float)cnt;
    dinv[i] = d > 0.0f ? rsqrtf(d) : 0.0f;
  }
  int v = cnt;
#pragma unroll
  for (int off = 1; off < 64; off <<= 1) {
    int u = __shfl_up(v, off, 64);
    if (lane >= off) v += u;
  }
  if (lane == 63) ws[w] = v;
  __syncthreads();
  int wexcl = 0;
#pragma unroll
  for (int k = 0; k < 4; ++k) wexcl += (k < w) ? ws[k] : 0;
  if (i < n) lex[i] = wexcl + v - cnt;
  if (tid == 255) bsum[blockIdx.x] = wexcl + v;
}

__global__ __launch_bounds__(256) void scan2_kernel(const int* __restrict__ bsum,
                                                    int* __restrict__ boff,
                                                    int* __restrict__ row_end, int nb) {
  __shared__ int ws[4];
  int tid = threadIdx.x, lane = tid & 63, w = tid >> 6;
  int cnt = (tid < nb) ? bsum[tid] : 0;
  int v = cnt;
#pragma unroll
  for (int off = 1; off < 64; off <<= 1) {
    int u = __shfl_up(v, off, 64);
    if (lane >= off) v += u;
  }
  if (lane == 63) ws[w] = v;
  __syncthreads();
  int wexcl = 0;
#pragma unroll
  for (int k = 0; k < 4; ++k) wexcl += (k < w) ? ws[k] : 0;
  if (tid < nb) boff[tid] = wexcl + v - cnt;
  if (tid == 255) *row_end = wexcl + v;
}

__global__ __launch_bounds__(256) void scan3_kernel(const int* __restrict__ lex,
                                                    const int* __restrict__ boff,
                                                    int* __restrict__ row_start,
                                                    int* __restrict__ fill_ptr, int n) {
  int i = blockIdx.x * 256 + threadIdx.x;
  if (i < n) {
    int rs = lex[i] + boff[blockIdx.x];
    row_start[i] = rs;
    fill_ptr[i] = rs;
  }
}

__global__ __launch_bounds__(256) void fill_kernel(const int* __restrict__ ei,
                                                   const float* __restrict__ dinv,
                                                   int* __restrict__ fill_ptr,
                                                   unsigned int* __restrict__ csr, int E) {
  int e = blockIdx.x * 256 + threadIdx.x;
  if (e < E) {
    int s = ei[e];
    int d = ei[E + e];
    int pos = atomicAdd(&fill_ptr[d], 1);
    float mag = dinv[s] * dinv[d];
    unsigned int bits = __float_as_uint(mag);
    unsigned int pk = (unsigned int)s << 12;
    if (bits != 0u) {
      bits += 0x4000u;  // round at bit 15 (carry propagates into exponent)
      int ex = (int)((bits >> 23) & 255u) - 112;
      ex = max(0, min(15, ex));
      pk |= ((unsigned int)ex << 8) | ((bits >> 15) & 0xffu);
    }
    csr[pos] = pk;
  }
}

// merged: x fp32 -> bf16 slab layout (first nx elems) and conv_w transpose -> Wt
// bf16 (next nw). nw covers layers 0..4 only; layer 5 goes through vk_kernel.
__global__ __launch_bounds__(256) void cvt_kernel(const float* __restrict__ x,
                                                  unsigned short* __restrict__ xo,
                                                  const float* __restrict__ w,
                                                  unsigned short* __restrict__ wt,
                                                  int nx, int nw) {
  int i = blockIdx.x * 256 + threadIdx.x;
  if (i < nx) {
    int nd = i >> 7, c = i & 127;
    xo[slab_off(c, nd)] = f2bf(x[i]);
  } else if (i < nx + nw) {
    int j = i - nx;
    int l = j / (WID * 640);
    int r = j % (WID * 640);
    int col = r / 640;
    int k = r % 640;
    int kk = k >> 7, m = k & 127;
    wt[j] = f2bf(w[(((size_t)l * 5 + kk) * WID + m) * WID + col]);
  }
}

// final-layer weight collapse: V[k][i] = sum_j conv_w[5][k][i][j] * lin_w[j]
// cst = sum_c conv_b[5][c]*lin_w[c] + lin_b.  3 blocks, one dot per thread.
__global__ __launch_bounds__(256) void vk_kernel(const float* __restrict__ w,
                                                 const float* __restrict__ b,
                                                 const float* __restrict__ lw,
                                                 const float* __restrict__ lb,
                                                 float* __restrict__ V,
                                                 float* __restrict__ cst) {
  int idx = blockIdx.x * 256 + threadIdx.x;
  if (idx < 5 * WID) {
    int k = idx / WID, i = idx % WID;
    const float4* wr = (const float4*)(w + (((size_t)5 * 5 + k) * WID + i) * WID);
    const float4* l4 = (const float4*)lw;
    float s = 0.f;
#pragma unroll 8
    for (int j = 0; j < WID / 4; ++j) {
      float4 a = wr[j], c = l4[j];
      s += a.x * c.x + a.y * c.y + a.z * c.z + a.w * c.w;
    }
    V[idx] = s;
  }
  if (blockIdx.x == 0 && threadIdx.x == 0) {
    float s = 0.f;
    for (int c = 0; c < WID; ++c) s += b[5 * WID + c] * lw[c];
    *cst = s + lb[0];
  }
}

// ---------------- propagate: out(bf16 slab) = scale*(L_hat @ xin) - sub -----------
// R21: quarter q = (blockIdx&7)>>1 works ONLY on slab q (N*64B = 3.2MB < 4MB L2).
// 4 lanes/node (16B = 8ch each), 64 node-slots/256-thr block, 512 blocks/quarter.

__global__ __launch_bounds__(256) void prop_kernel(unsigned short* __restrict__ out,
                                                   const unsigned short* __restrict__ xin,
                                                   const unsigned short* __restrict__ sub,
                                                   float scale,
                                                   const int* __restrict__ row_start,
                                                   const unsigned int* __restrict__ csr,
                                                   int n) {
  int t = threadIdx.x & 3;          // lane within 4-lane node group
  int slot = threadIdx.x >> 2;      // 0..63 node slots
  int xcd = blockIdx.x & 7;
  int q = xcd >> 1;                 // slab / channel quarter 0..3
  int r = ((blockIdx.x >> 3) << 1) | (xcd & 1);  // rank within quarter 0..511
  const unsigned short* xq = xin + (size_t)q * NN * 32;
  unsigned short* oq = out + (size_t)q * NN * 32;

  for (int node = r * 64 + slot; node < n; node += 512 * 64) {
    int s = row_start[node], e = row_start[node + 1];
    float a0 = 0.f, a1 = 0.f, a2 = 0.f, a3 = 0.f;
    float a4 = 0.f, a5 = 0.f, a6 = 0.f, a7 = 0.f;
    for (int base = s; base < e; base += 4) {
      int cnt = min(4, e - base);
      unsigned int ed = (t < cnt) ? csr[base + t] : 0u;
      if (cnt == 4) {
        unsigned int p0 = (unsigned int)__shfl((int)ed, 0, 4);
        unsigned int p1 = (unsigned int)__shfl((int)ed, 1, 4);
        unsigned int p2 = (unsigned int)__shfl((int)ed, 2, 4);
        unsigned int p3 = (unsigned int)__shfl((int)ed, 3, 4);
        int s0 = p0 >> 12, s1 = p1 >> 12, s2 = p2 >> 12, s3 = p3 >> 12;
        float n0 = dec_norm(p0), n1 = dec_norm(p1), n2 = dec_norm(p2), n3 = dec_norm(p3);
        const uint4 v0 = *(const uint4*)(xq + (size_t)s0 * 32 + t * 8);
        const uint4 v1 = *(const uint4*)(xq + (size_t)s1 * 32 + t * 8);
        const uint4 v2 = *(const uint4*)(xq + (size_t)s2 * 32 + t * 8);
        const uint4 v3 = *(const uint4*)(xq + (size_t)s3 * 32 + t * 8);
        a0 += n0 * bflo(v0.x) + n1 * bflo(v1.x) + n2 * bflo(v2.x) + n3 * bflo(v3.x);
        a1 += n0 * bfhi(v0.x) + n1 * bfhi(v1.x) + n2 * bfhi(v2.x) + n3 * bfhi(v3.x);
        a2 += n0 * bflo(v0.y) + n1 * bflo(v1.y) + n2 * bflo(v2.y) + n3 * bflo(v3.y);
        a3 += n0 * bfhi(v0.y) + n1 * bfhi(v1.y) + n2 * bfhi(v2.y) + n3 * bfhi(v3.y);
        a4 += n0 * bflo(v0.z) + n1 * bflo(v1.z) + n2 * bflo(v2.z) + n3 * bflo(v3.z);
        a5 += n0 * bfhi(v0.z) + n1 * bfhi(v1.z) + n2 * bfhi(v2.z) + n3 * bfhi(v3.z);
        a6 += n0 * bflo(v0.w) + n1 * bflo(v1.w) + n2 * bflo(v2.w) + n3 * bflo(v3.w);
        a7 += n0 * bfhi(v0.w) + n1 * bfhi(v1.w) + n2 * bfhi(v2.w) + n3 * bfhi(v3.w);
      } else {
        for (int j = 0; j < cnt; ++j) {
          unsigned int pj = (unsigned int)__shfl((int)ed, j, 4);
          int sj = pj >> 12;
          float nj = dec_norm(pj);
          const uint4 v = *(const uint4*)(xq + (size_t)sj * 32 + t * 8);
          a0 += nj * bflo(v.x); a1 += nj * bfhi(v.x);
          a2 += nj * bflo(v.y); a3 += nj * bfhi(v.y);
          a4 += nj * bflo(v.z); a5 += nj * bfhi(v.z);
          a6 += nj * bflo(v.w); a7 += nj * bfhi(v.w);
        }
      }
    }
    size_t o = (size_t)node * 32 + t * 8;
    float r0 = scale * a0, r1 = scale * a1, r2 = scale * a2, r3 = scale * a3;
    float r4 = scale * a4, r5 = scale * a5, r6 = scale * a6, r7 = scale * a7;
    if (sub) {
      const uint4 sv = *(const uint4*)(sub + (size_t)q * NN * 32 + o);
      r0 -= bflo(sv.x); r1 -= bfhi(sv.x);
      r2 -= bflo(sv.y); r3 -= bfhi(sv.y);
      r4 -= bflo(sv.z); r5 -= bfhi(sv.z);
      r6 -= bflo(sv.w); r7 -= bfhi(sv.w);
    }
    uint4 wv;
    wv.x = pack2(r0, r1); wv.y = pack2(r2, r3);
    wv.z = pack2(r4, r5); wv.w = pack2(r6, r7);
    *(uint4*)(oq + o) = wv;
  }
}

// ---------------- final layer: skinny fp32 path ----------------
// U[n][0..4] = H[n][:] @ v_k ; U[n][5..7]=0 ; y[n] = U[n][0] + cst. H is slab bf16.
__global__ __launch_bounds__(256) void final_proj(const unsigned short* __restrict__ H,
                                                  const float* __restrict__ V,
                                                  const float* __restrict__ cstp,
                                                  float* __restrict__ U,
                                                  float* __restrict__ y, int n) {
  int t = threadIdx.x & 15;
  int node = blockIdx.x * 16 + (threadIdx.x >> 4);
  if (node >= n) return;
  const uint4 h = *(const uint4*)(H + slab_off(t * 8, node));
  float hv0 = bflo(h.x), hv1 = bfhi(h.x), hv2 = bflo(h.y), hv3 = bfhi(h.y);
  float hv4 = bflo(h.z), hv5 = bfhi(h.z), hv6 = bflo(h.w), hv7 = bfhi(h.w);
  float p[5];
#pragma unroll
  for (int k = 0; k < 5; ++k) {
    const float4* vp = (const float4*)(V + k * WID + t * 8);
    float4 v0 = vp[0], v1 = vp[1];
    float s = hv0 * v0.x + hv1 * v0.y + hv2 * v0.z + hv3 * v0.w +
              hv4 * v1.x + hv5 * v1.y + hv6 * v1.z + hv7 * v1.w;
#pragma unroll
    for (int off = 1; off < 16; off <<= 1) s += __shfl_xor(s, off, 16);
    p[k] = s;
  }
  if (t == 0) {
    float4 u0 = {p[0], p[1], p[2], p[3]};
    float4 u1 = {p[4], 0.f, 0.f, 0.f};
    *(float4*)(U + (size_t)node * 8) = u0;
    *(float4*)(U + (size_t)node * 8 + 4) = u1;
    y[node] = p[0] + *cstp;
  }
}

// 8-wide fp32 prop: out[n][:] = scale*(L_hat @ xin)[n][:] - sub[n][:]
// y[n] += out[n][pick].  Table is N*32B = 1.6MB -> L2-resident gathers.
__global__ __launch_bounds__(256) void prop_small(float* __restrict__ out,
                                                  const float* __restrict__ xin,
                                                  const float* __restrict__ sub,
                                                  float scale, int pick,
                                                  float* __restrict__ y,
                                                  const int* __restrict__ row_start,
                                                  const unsigned int* __restrict__ csr,
                                                  int n) {
  int node = blockIdx.x * 256 + threadIdx.x;
  if (node >= n) return;
  int s = row_start[node], e = row_start[node + 1];
  float a0 = 0.f, a1 = 0.f, a2 = 0.f, a3 = 0.f;
  float a4 = 0.f, a5 = 0.f, a6 = 0.f, a7 = 0.f;
  for (int i = s; i < e; ++i) {
    unsigned int p = csr[i];
    int src = (int)(p >> 12);
    float nv = dec_norm(p);
    const float4* r = (const float4*)(xin + (size_t)src * 8);
    float4 v0 = r[0], v1 = r[1];
    a0 += nv * v0.x; a1 += nv * v0.y; a2 += nv * v0.z; a3 += nv * v0.w;
    a4 += nv * v1.x; a5 += nv * v1.y; a6 += nv * v1.z; a7 += nv * v1.w;
  }
  float o0 = scale * a0, o1 = scale * a1, o2 = scale * a2, o3 = scale * a3;
  float o4 = scale * a4, o5 = scale * a5, o6 = scale * a6, o7 = scale * a7;
  if (sub) {
    const float4* sv = (const float4*)(sub + (size_t)node * 8);
    float4 s0 = sv[0], s1 = sv[1];
    o0 -= s0.x; o1 -= s0.y; o2 -= s0.z; o3 -= s0.w;
    o4 -= s1.x; o5 -= s1.y; o6 -= s1.z; o7 -= s1.w;
  }
  float4 w0 = {o0, o1, o2, o3};
  float4 w1 = {o4, o5, o6, o7};
  *(float4*)(out + (size_t)node * 8) = w0;
  *(float4*)(out + (size_t)node * 8 + 4) = w1;
  // static select (avoid runtime-indexed array -> scratch, rule #20)
  float yp = o1;
  if (pick == 2) yp = o2;
  if (pick == 3) yp = o3;
  if (pick == 4) yp = o4;
  y[node] += yp;
}

// ---------------- fused layer GEMM: H[N,128] = A[N,640](bf16 slabs) @ W[640,128] + b --
// R18: 512 thr = 8 waves; block tile 128 rows x 128 cols (wave w: rows w*16..w*16+15).
// BK=64, 10 k-chunks, LDS As[128][72] + Bs[128][72] (36.9 KB). A addresses go
// through slab_off (each 16-short segment lies fully inside one slab). Register
// prefetch of chunk kc+1 after barrier1; ReLU epilogue, bf16 slab out.

__global__ __launch_bounds__(512) void cheb_gemm(
    const unsigned short* __restrict__ T0, const unsigned short* __restrict__ T1,
    const unsigned short* __restrict__ T2, const unsigned short* __restrict__ T3,
    const unsigned short* __restrict__ T4,
    const unsigned short* __restrict__ Wt,
    const float* __restrict__ bias,
    unsigned short* __restrict__ Hb, int M) {
  __shared__ unsigned short As[128][72];  // [row][k 0..63], pad to 72
  __shared__ unsigned short Bs[128][72];  // [col][k 0..63]
  const unsigned short* chunks[5] = {T0, T1, T2, T3, T4};
  int tid = threadIdx.x;
  int wave = tid >> 6, lane = tid & 63;
  int lrow = lane & 15, quad = lane >> 4;
  int rowBase = blockIdx.x * 128;

  f32x4 acc[8];
#pragma unroll
  for (int b = 0; b < 8; ++b) acc[b] = (f32x4){0.f, 0.f, 0.f, 0.f};

  // staging coords: A rows 0..127 (4 thr/row), B cols 0..127 (4 thr/col);
  // each thread stages 2x int4 (16 shorts) for A and for B.
  int ar = tid >> 2, aseg = (tid & 3) * 16;
  int agrow = min(rowBase + ar, M - 1);  // clamp (garbage rows never stored)
  int bc = tid >> 2, bseg = (tid & 3) * 16;

  int4 aR0, aR1, bR0, bR1;
  {
    const unsigned short* ap = chunks[0] + slab_off(aseg, agrow);
    aR0 = *(const int4*)ap;
    aR1 = *(const int4*)(ap + 8);
    const unsigned short* bp = Wt + (size_t)bc * 640 + bseg;
    bR0 = *(const int4*)bp;
    bR1 = *(const int4*)(bp + 8);
  }

  for (int kc = 0; kc < 10; ++kc) {
    *(int4*)(&As[ar][aseg]) = aR0;
    *(int4*)(&As[ar][aseg + 8]) = aR1;
    *(int4*)(&Bs[bc][bseg]) = bR0;
    *(int4*)(&Bs[bc][bseg + 8]) = bR1;
    __syncthreads();

    if (kc < 9) {  // prefetch next chunk; overlaps the 16 MFMAs below
      int kn = kc + 1;
      const unsigned short* ap =
          chunks[kn >> 1] + slab_off((kn & 1) * 64 + aseg, agrow);
      aR0 = *(const int4*)ap;
      aR1 = *(const int4*)(ap + 8);
      const unsigned short* bp = Wt + (size_t)bc * 640 + kn * 64 + bseg;
      bR0 = *(const int4*)bp;
      bR1 = *(const int4*)(bp + 8);
    }

    bf16x8 a0 = *(bf16x8*)(&As[wave * 16 + lrow][quad * 8]);
    bf16x8 a1 = *(bf16x8*)(&As[wave * 16 + lrow][32 + quad * 8]);
#pragma unroll
    for (int ct = 0; ct < 8; ++ct) {
      bf16x8 b0 = *(bf16x8*)(&Bs[ct * 16 + lrow][quad * 8]);
      acc[ct] = __builtin_amdgcn_mfma_f32_16x16x32_bf16(a0, b0, acc[ct], 0, 0, 0);
      bf16x8 b1 = *(bf16x8*)(&Bs[ct * 16 + lrow][32 + quad * 8]);
      acc[ct] = __builtin_amdgcn_mfma_f32_16x16x32_bf16(a1, b1, acc[ct], 0, 0, 0);
    }
    __syncthreads();
  }

  // epilogue: C/D layout col=lane&15, row=quad*4+reg ; wave rows rowBase+wave*16+...
#pragma unroll
  for (int ct = 0; ct < 8; ++ct) {
    int gcol = ct * 16 + lrow;
    float bv = bias[gcol];
#pragma unroll
    for (int reg = 0; reg < 4; ++reg) {
      int grow = rowBase + wave * 16 + quad * 4 + reg;
      if (grow < M) {
        float v = fmaxf(acc[ct][reg] + bv, 0.f);
        Hb[slab_off(gcol, grow)] = f2bf(v);
      }
    }
  }
}

// ---------------- host orchestration ----------------

extern "C" void kernel_launch(void* const* d_in, const int* in_sizes, int n_in,
                              void* d_out, int out_size, void* d_ws, size_t ws_size,
                              hipStream_t stream) {
  const float* x = (const float*)d_in[0];
  const int* ei = (const int*)d_in[1];          // int32 per harness contract
  const float* conv_w = (const float*)d_in[2];  // [6][5][128][128]
  const float* conv_b = (const float*)d_in[3];  // [6][128]
  const float* lin_w = (const float*)d_in[4];   // [128]
  const float* lin_b = (const float*)d_in[5];   // [1]

  const int N = NN, E = NE, C = WID, L = 6;
  const int NB = (N + 255) / 256;

  char* ws = (char*)d_ws;
  size_t off = 0;
  auto alloc = [&](size_t bytes) -> void* {
    void* p = ws + off;
    off = (off + bytes + 255) & ~(size_t)255;
    return p;
  };
  int* deg = (int*)alloc((size_t)N * 4);
  float* dinv = (float*)alloc((size_t)N * 4);
  int* row_start = (int*)alloc((size_t)(N + 1) * 4);
  int* fill_ptr = (int*)alloc((size_t)N * 4);
  int* lex = (int*)alloc((size_t)N * 4);
  int* bsum = (int*)alloc((size_t)NB * 4);
  int* boff = (int*)alloc((size_t)NB * 4);
  unsigned int* csr = (unsigned int*)alloc((size_t)E * 4);
  unsigned short* Xbf = (unsigned short*)alloc((size_t)N * C * 2);
  unsigned short* Hb0 = (unsigned short*)alloc((size_t)N * C * 2);
  unsigned short* Hb1 = (unsigned short*)alloc((size_t)N * C * 2);
  unsigned short* T1b = (unsigned short*)alloc((size_t)N * C * 2);
  unsigned short* T2b = (unsigned short*)alloc((size_t)N * C * 2);
  unsigned short* T3b = (unsigned short*)alloc((size_t)N * C * 2);
  unsigned short* T4b = (unsigned short*)alloc((size_t)N * C * 2);
  unsigned short* Wt = (unsigned short*)alloc((size_t)5 * C * 640 * 2);
  float* V = (float*)alloc((size_t)5 * C * 4);
  float* cst = (float*)alloc(4);

  // preprocessing
  hipMemsetAsync(deg, 0, (size_t)N * 4, stream);
  degree_kernel<<<(E + 255) / 256, 256, 0, stream>>>(ei, deg, E);
  scan1_kernel<<<NB, 256, 0, stream>>>(deg, lex, bsum, dinv, N);
  scan2_kernel<<<1, 256, 0, stream>>>(bsum, boff, &row_start[N], NB);
  scan3_kernel<<<NB, 256, 0, stream>>>(lex, boff, row_start, fill_ptr, N);
  fill_kernel<<<(E + 255) / 256, 256, 0, stream>>>(ei, dinv, fill_ptr, csr, E);
  {
    int nx = N * C, nw = 5 * C * 640;  // layer-5 weights collapse via vk_kernel
    cvt_kernel<<<(nx + nw + 255) / 256, 256, 0, stream>>>(x, Xbf, conv_w, Wt, nx, nw);
  }
  vk_kernel<<<3, 256, 0, stream>>>(conv_w, conv_b, lin_w, lin_b, V, cst);

  const int gg = (N + 127) / 128;  // gemm grid (128 rows/block)

  // layers 0..4: full-width props + MFMA GEMM + ReLU
  for (int l = 0; l < 5; ++l) {
    const unsigned short* T0 = (l == 0) ? Xbf : ((l & 1) ? Hb0 : Hb1);
    unsigned short* Hb = (l & 1) ? Hb1 : Hb0;

    prop_kernel<<<PROP_BLOCKS, 256, 0, stream>>>(T1b, T0, nullptr, 1.0f, row_start, csr, N);
    prop_kernel<<<PROP_BLOCKS, 256, 0, stream>>>(T2b, T1b, T0, 2.0f, row_start, csr, N);
    prop_kernel<<<PROP_BLOCKS, 256, 0, stream>>>(T3b, T2b, T1b, 2.0f, row_start, csr, N);
    prop_kernel<<<PROP_BLOCKS, 256, 0, stream>>>(T4b, T3b, T2b, 2.0f, row_start, csr, N);
    cheb_gemm<<<gg, 512, 0, stream>>>(T0, T1b, T2b, T3b, T4b,
                                      Wt + (size_t)l * C * 640, conv_b + (size_t)l * C,
                                      Hb, N);
  }

  // final layer (l=5): y = sum_k T_k(L) (H v_k) + cst -- 5-wide fp32 recurrence.
  // H = Hb0 (layer 4 output, slab bf16). Reuse T-buffers as fp32 [N][8] (1.6MB).
  {
    float* y = (float*)d_out;
    float* U  = (float*)T1b;
    float* P1 = (float*)T2b;
    float* P2 = (float*)T3b;
    float* P3 = (float*)T4b;
    float* P4 = (float*)Xbf;
    const int pg = (N + 255) / 256;
    final_proj<<<(N + 15) / 16, 256, 0, stream>>>(Hb0, V, cst, U, y, N);
    prop_small<<<pg, 256, 0, stream>>>(P1, U, nullptr, 1.0f, 1, y, row_start, csr, N);
    prop_small<<<pg, 256, 0, stream>>>(P2, P1, U, 2.0f, 2, y, row_start, csr, N);
    prop_small<<<pg, 256, 0, stream>>>(P3, P2, P1, 2.0f, 3, y, row_start, csr, N);
    prop_small<<<pg, 256, 0, stream>>>(P4, P3, P2, 2.0f, 4, y, row_start, csr, N);
  }
}

// Round 9
// 833.034 us; speedup vs baseline: 1.3076x; 1.0586x over previous
//
#include <hip/hip_runtime.h>

// ChebConv GNN: 6 layers x (K=5 Chebyshev), 50000 nodes / 640000 edges, WIDTH=128.
//  - CSR packed to 4B/edge: {src:20 | exp4 | mant8} (norm = -m*2^(e-112)).
//  - All Chebyshev T_k stored bf16 interleaved [N][128]; prop: GRID-STRIDE 2048
//    blocks, 16 lanes/node, uint4 gathers, shfl-broadcast descriptors, 4-deep
//    unroll (R11: 8-deep regresses). fp32 accumulate.
//  - R20/R21 (FAILED, REVERTED): L2-locality partitioning. Interleaved quarters
//    split cache lines (FETCH 72->110MB, 40us); slab quarters fixed bytes but
//    doubled transaction count (64B rows: 16 trans/KB vs 8) -> ~30us. Props are
//    TRANSACTION-RATE-limited; per-XCD table reuse is structurally ~0.8
//    touches/line (matches 72MB FETCH). L2-partitioning direction falsified.
//  - R22: W-MERGE: out = T0 W0 + T1 W1 + T2 (W2-W4) + T3 W3 + (L*T3) (2 W4)
//    -- the 4th prop per layer becomes Z = L*T3 (no sub read, no subtract).
//    Weight combination folded into cvt_kernel.
//  - R15-17: degree-sorting NEUTRAL (3-round A/B).
//  - R17 lesson: never co-locate a latency-bound gather phase with an LDS-heavy
//    MFMA phase in one block (45KB LDS fusion: Occ 18%, 72us/dispatch).
//  - R18: GEMM tile 128x128, 512 thr, 8 waves, LDS 36.9KB (838.6us total).
//  - FINAL LAYER (R14): y = sum_k T_k(L) (H (W_k w_lin)) + const; 5-wide fp32
//    recurrence (prop_small) replaces 4 full props + full GEMM.
//  NOTE (R9): __builtin_nontemporal_* scalarizes vector accesses on gfx950 - avoid.
//  NOTE (R12/13): cooperative launch no-ops; software grid barriers cost 10x.

#define NN 50000
#define NE 640000
#define WID 128
#define PROP_BLOCKS 2048

typedef __attribute__((ext_vector_type(8))) short bf16x8;
typedef __attribute__((ext_vector_type(4))) float f32x4;

__device__ __forceinline__ unsigned short f2bf(float f) {
  union { float f; unsigned int u; } v; v.f = f;
  unsigned int r = v.u + 0x7FFF + ((v.u >> 16) & 1);  // RNE
  return (unsigned short)(r >> 16);
}
__device__ __forceinline__ unsigned int pack2(float lo, float hi) {
  return (unsigned int)f2bf(lo) | ((unsigned int)f2bf(hi) << 16);
}
__device__ __forceinline__ float bflo(unsigned int u) {
  return __uint_as_float(u << 16);
}
__device__ __forceinline__ float bfhi(unsigned int u) {
  return __uint_as_float(u & 0xffff0000u);
}
// decode packed edge: bits 11..8 = exp-112, 7..0 = mant (norm is negative)
__device__ __forceinline__ float dec_norm(unsigned int p) {
  unsigned int lo = p & 0xfffu;
  float v = -__uint_as_float(((112u + ((p >> 8) & 15u)) << 23) | ((p & 255u) << 15));
  return (lo == 0u) ? 0.f : v;
}

// ---------------- preprocessing ----------------

__global__ __launch_bounds__(256) void degree_kernel(const int* __restrict__ ei,
                                                     int* __restrict__ deg, int E) {
  int e = blockIdx.x * 256 + threadIdx.x;
  if (e < E) atomicAdd(&deg[ei[E + e]], 1);
}

__global__ __launch_bounds__(256) void scan1_kernel(const int* __restrict__ deg,
                                                    int* __restrict__ lex,
                                                    int* __restrict__ bsum,
                                                    float* __restrict__ dinv, int n) {
  __shared__ int ws[4];
  int tid = threadIdx.x, lane = tid & 63, w = tid >> 6;
  int i = blockIdx.x * 256 + tid;
  int cnt = (i < n) ? deg[i] : 0;
  if (i < n) {
    float d = (float)cnt;
    dinv[i] = d > 0.0f ? rsqrtf(d) : 0.0f;
  }
  int v = cnt;
#pragma unroll
  for (int off = 1; off < 64; off <<= 1) {
    int u = __shfl_up(v, off, 64);
    if (lane >= off) v += u;
  }
  if (lane == 63) ws[w] = v;
  __syncthreads();
  int wexcl = 0;
#pragma unroll
  for (int k = 0; k < 4; ++k) wexcl += (k < w) ? ws[k] : 0;
  if (i < n) lex[i] = wexcl + v - cnt;
  if (tid == 255) bsum[blockIdx.x] = wexcl + v;
}

__global__ __launch_bounds__(256) void scan2_kernel(const int* __restrict__ bsum,
                                                    int* __restrict__ boff,
                                                    int* __restrict__ row_end, int nb) {
  __shared__ int ws[4];
  int tid = threadIdx.x, lane = tid & 63, w = tid >> 6;
  int cnt = (tid < nb) ? bsum[tid] : 0;
  int v = cnt;
#pragma unroll
  for (int off = 1; off < 64; off <<= 1) {
    int u = __shfl_up(v, off, 64);
    if (lane >= off) v += u;
  }
  if (lane == 63) ws[w] = v;
  __syncthreads();
  int wexcl = 0;
#pragma unroll
  for (int k = 0; k < 4; ++k) wexcl += (k < w) ? ws[k] : 0;
  if (tid < nb) boff[tid] = wexcl + v - cnt;
  if (tid == 255) *row_end = wexcl + v;
}

__global__ __launch_bounds__(256) void scan3_kernel(const int* __restrict__ lex,
                                                    const int* __restrict__ boff,
                                                    int* __restrict__ row_start,
                                                    int* __restrict__ fill_ptr, int n) {
  int i = blockIdx.x * 256 + threadIdx.x;
  if (i < n) {
    int rs = lex[i] + boff[blockIdx.x];
    row_start[i] = rs;
    fill_ptr[i] = rs;
  }
}

__global__ __launch_bounds__(256) void fill_kernel(const int* __restrict__ ei,
                                                   const float* __restrict__ dinv,
                                                   int* __restrict__ fill_ptr,
                                                   unsigned int* __restrict__ csr, int E) {
  int e = blockIdx.x * 256 + threadIdx.x;
  if (e < E) {
    int s = ei[e];
    int d = ei[E + e];
    int pos = atomicAdd(&fill_ptr[d], 1);
    float mag = dinv[s] * dinv[d];
    unsigned int bits = __float_as_uint(mag);
    unsigned int pk = (unsigned int)s << 12;
    if (bits != 0u) {
      bits += 0x4000u;  // round at bit 15 (carry propagates into exponent)
      int ex = (int)((bits >> 23) & 255u) - 112;
      ex = max(0, min(15, ex));
      pk |= ((unsigned int)ex << 8) | ((bits >> 15) & 0xffu);
    }
    csr[pos] = pk;
  }
}

// merged: x fp32 -> bf16 (first nx elems) and conv_w transpose -> Wt bf16 (next nw).
// R22 W-merge: chunk kk=2 stores W2-W4, chunk kk=4 stores 2*W4 (the 4th prop per
// layer then computes Z = L*T3 without the Chebyshev subtract).
// nw covers layers 0..4 only; layer 5's weights go through vk_kernel instead.
__global__ __launch_bounds__(256) void cvt_kernel(const float* __restrict__ x,
                                                  unsigned short* __restrict__ xo,
                                                  const float* __restrict__ w,
                                                  unsigned short* __restrict__ wt,
                                                  int nx, int nw) {
  int i = blockIdx.x * 256 + threadIdx.x;
  if (i < nx) {
    xo[i] = f2bf(x[i]);
  } else if (i < nx + nw) {
    int j = i - nx;
    int l = j / (WID * 640);
    int r = j % (WID * 640);
    int col = r / 640;
    int k = r % 640;
    int kk = k >> 7, m = k & 127;
    float wv = w[(((size_t)l * 5 + kk) * WID + m) * WID + col];
    if (kk == 2) wv -= w[(((size_t)l * 5 + 4) * WID + m) * WID + col];
    else if (kk == 4) wv *= 2.0f;
    wt[j] = f2bf(wv);
  }
}

// final-layer weight collapse: V[k][i] = sum_j conv_w[5][k][i][j] * lin_w[j]
// cst = sum_c conv_b[5][c]*lin_w[c] + lin_b.  3 blocks, one dot per thread.
__global__ __launch_bounds__(256) void vk_kernel(const float* __restrict__ w,
                                                 const float* __restrict__ b,
                                                 const float* __restrict__ lw,
                                                 const float* __restrict__ lb,
                                                 float* __restrict__ V,
                                                 float* __restrict__ cst) {
  int idx = blockIdx.x * 256 + threadIdx.x;
  if (idx < 5 * WID) {
    int k = idx / WID, i = idx % WID;
    const float4* wr = (const float4*)(w + (((size_t)5 * 5 + k) * WID + i) * WID);
    const float4* l4 = (const float4*)lw;
    float s = 0.f;
#pragma unroll 8
    for (int j = 0; j < WID / 4; ++j) {
      float4 a = wr[j], c = l4[j];
      s += a.x * c.x + a.y * c.y + a.z * c.z + a.w * c.w;
    }
    V[idx] = s;
  }
  if (blockIdx.x == 0 && threadIdx.x == 0) {
    float s = 0.f;
    for (int c = 0; c < WID; ++c) s += b[5 * WID + c] * lw[c];
    *cst = s + lb[0];
  }
}

// ---------------- propagate: out(bf16) = scale * (L_hat @ xin(bf16)) - sub(bf16) ----------
// Grid-stride over nodes with PROP_BLOCKS blocks (8/CU resident, no dispatch ramp).
// 16 lanes/node (16B = 8ch per lane), 16 node-slots per 256-thr block.

__global__ __launch_bounds__(256) void prop_kernel(unsigned short* __restrict__ out,
                                                   const unsigned short* __restrict__ xin,
                                                   const unsigned short* __restrict__ sub,
                                                   float scale,
                                                   const int* __restrict__ row_start,
                                                   const unsigned int* __restrict__ csr,
                                                   int n) {
  int t = threadIdx.x & 15;
  for (int node = blockIdx.x * 16 + (threadIdx.x >> 4); node < n;
       node += PROP_BLOCKS * 16) {
    int s = row_start[node], e = row_start[node + 1];
    float a0 = 0.f, a1 = 0.f, a2 = 0.f, a3 = 0.f;
    float a4 = 0.f, a5 = 0.f, a6 = 0.f, a7 = 0.f;
    for (int base = s; base < e; base += 16) {
      int cnt = min(16, e - base);
      unsigned int ed = (t < cnt) ? csr[base + t] : 0u;
      int j = 0;
      for (; j + 4 <= cnt; j += 4) {
        unsigned int p0 = (unsigned int)__shfl((int)ed, j, 16);
        unsigned int p1 = (unsigned int)__shfl((int)ed, j + 1, 16);
        unsigned int p2 = (unsigned int)__shfl((int)ed, j + 2, 16);
        unsigned int p3 = (unsigned int)__shfl((int)ed, j + 3, 16);
        int s0 = p0 >> 12, s1 = p1 >> 12, s2 = p2 >> 12, s3 = p3 >> 12;
        float n0 = dec_norm(p0), n1 = dec_norm(p1), n2 = dec_norm(p2), n3 = dec_norm(p3);
        const uint4 v0 = *(const uint4*)(xin + (size_t)s0 * WID + t * 8);
        const uint4 v1 = *(const uint4*)(xin + (size_t)s1 * WID + t * 8);
        const uint4 v2 = *(const uint4*)(xin + (size_t)s2 * WID + t * 8);
        const uint4 v3 = *(const uint4*)(xin + (size_t)s3 * WID + t * 8);
        a0 += n0 * bflo(v0.x) + n1 * bflo(v1.x) + n2 * bflo(v2.x) + n3 * bflo(v3.x);
        a1 += n0 * bfhi(v0.x) + n1 * bfhi(v1.x) + n2 * bfhi(v2.x) + n3 * bfhi(v3.x);
        a2 += n0 * bflo(v0.y) + n1 * bflo(v1.y) + n2 * bflo(v2.y) + n3 * bflo(v3.y);
        a3 += n0 * bfhi(v0.y) + n1 * bfhi(v1.y) + n2 * bfhi(v2.y) + n3 * bfhi(v3.y);
        a4 += n0 * bflo(v0.z) + n1 * bflo(v1.z) + n2 * bflo(v2.z) + n3 * bflo(v3.z);
        a5 += n0 * bfhi(v0.z) + n1 * bfhi(v1.z) + n2 * bfhi(v2.z) + n3 * bfhi(v3.z);
        a6 += n0 * bflo(v0.w) + n1 * bflo(v1.w) + n2 * bflo(v2.w) + n3 * bflo(v3.w);
        a7 += n0 * bfhi(v0.w) + n1 * bfhi(v1.w) + n2 * bfhi(v2.w) + n3 * bfhi(v3.w);
      }
      for (; j < cnt; ++j) {
        unsigned int pj = (unsigned int)__shfl((int)ed, j, 16);
        int sj = pj >> 12;
        float nj = dec_norm(pj);
        const uint4 v = *(const uint4*)(xin + (size_t)sj * WID + t * 8);
        a0 += nj * bflo(v.x); a1 += nj * bfhi(v.x);
        a2 += nj * bflo(v.y); a3 += nj * bfhi(v.y);
        a4 += nj * bflo(v.z); a5 += nj * bfhi(v.z);
        a6 += nj * bflo(v.w); a7 += nj * bfhi(v.w);
      }
    }
    size_t o = (size_t)node * WID + t * 8;
    float r0 = scale * a0, r1 = scale * a1, r2 = scale * a2, r3 = scale * a3;
    float r4 = scale * a4, r5 = scale * a5, r6 = scale * a6, r7 = scale * a7;
    if (sub) {
      const uint4 sv = *(const uint4*)(sub + o);
      r0 -= bflo(sv.x); r1 -= bfhi(sv.x);
      r2 -= bflo(sv.y); r3 -= bfhi(sv.y);
      r4 -= bflo(sv.z); r5 -= bfhi(sv.z);
      r6 -= bflo(sv.w); r7 -= bfhi(sv.w);
    }
    uint4 wv;
    wv.x = pack2(r0, r1); wv.y = pack2(r2, r3);
    wv.z = pack2(r4, r5); wv.w = pack2(r6, r7);
    *(uint4*)(out + o) = wv;
  }
}

// ---------------- final layer: skinny fp32 path ----------------
// U[n][0..4] = H[n][:] @ v_k ; U[n][5..7]=0 ; y[n] = U[n][0] + cst
__global__ __launch_bounds__(256) void final_proj(const unsigned short* __restrict__ H,
                                                  const float* __restrict__ V,
                                                  const float* __restrict__ cstp,
                                                  float* __restrict__ U,
                                                  float* __restrict__ y, int n) {
  int t = threadIdx.x & 15;
  int node = blockIdx.x * 16 + (threadIdx.x >> 4);
  if (node >= n) return;
  const uint4 h = *(const uint4*)(H + (size_t)node * WID + t * 8);
  float hv0 = bflo(h.x), hv1 = bfhi(h.x), hv2 = bflo(h.y), hv3 = bfhi(h.y);
  float hv4 = bflo(h.z), hv5 = bfhi(h.z), hv6 = bflo(h.w), hv7 = bfhi(h.w);
  float p[5];
#pragma unroll
  for (int k = 0; k < 5; ++k) {
    const float4* vp = (const float4*)(V + k * WID + t * 8);
    float4 v0 = vp[0], v1 = vp[1];
    float s = hv0 * v0.x + hv1 * v0.y + hv2 * v0.z + hv3 * v0.w +
              hv4 * v1.x + hv5 * v1.y + hv6 * v1.z + hv7 * v1.w;
#pragma unroll
    for (int off = 1; off < 16; off <<= 1) s += __shfl_xor(s, off, 16);
    p[k] = s;
  }
  if (t == 0) {
    float4 u0 = {p[0], p[1], p[2], p[3]};
    float4 u1 = {p[4], 0.f, 0.f, 0.f};
    *(float4*)(U + (size_t)node * 8) = u0;
    *(float4*)(U + (size_t)node * 8 + 4) = u1;
    y[node] = p[0] + *cstp;
  }
}

// 8-wide fp32 prop: out[n][:] = scale*(L_hat @ xin)[n][:] - sub[n][:]
// y[n] += out[n][pick].  Table is N*32B = 1.6MB -> L2-resident gathers.
__global__ __launch_bounds__(256) void prop_small(float* __restrict__ out,
                                                  const float* __restrict__ xin,
                                                  const float* __restrict__ sub,
                                                  float scale, int pick,
                                                  float* __restrict__ y,
                                                  const int* __restrict__ row_start,
                                                  const unsigned int* __restrict__ csr,
                                                  int n) {
  int node = blockIdx.x * 256 + threadIdx.x;
  if (node >= n) return;
  int s = row_start[node], e = row_start[node + 1];
  float a0 = 0.f, a1 = 0.f, a2 = 0.f, a3 = 0.f;
  float a4 = 0.f, a5 = 0.f, a6 = 0.f, a7 = 0.f;
  for (int i = s; i < e; ++i) {
    unsigned int p = csr[i];
    int src = (int)(p >> 12);
    float nv = dec_norm(p);
    const float4* r = (const float4*)(xin + (size_t)src * 8);
    float4 v0 = r[0], v1 = r[1];
    a0 += nv * v0.x; a1 += nv * v0.y; a2 += nv * v0.z; a3 += nv * v0.w;
    a4 += nv * v1.x; a5 += nv * v1.y; a6 += nv * v1.z; a7 += nv * v1.w;
  }
  float o0 = scale * a0, o1 = scale * a1, o2 = scale * a2, o3 = scale * a3;
  float o4 = scale * a4, o5 = scale * a5, o6 = scale * a6, o7 = scale * a7;
  if (sub) {
    const float4* sv = (const float4*)(sub + (size_t)node * 8);
    float4 s0 = sv[0], s1 = sv[1];
    o0 -= s0.x; o1 -= s0.y; o2 -= s0.z; o3 -= s0.w;
    o4 -= s1.x; o5 -= s1.y; o6 -= s1.z; o7 -= s1.w;
  }
  float4 w0 = {o0, o1, o2, o3};
  float4 w1 = {o4, o5, o6, o7};
  *(float4*)(out + (size_t)node * 8) = w0;
  *(float4*)(out + (size_t)node * 8 + 4) = w1;
  // static select (avoid runtime-indexed array -> scratch, rule #20)
  float yp = o1;
  if (pick == 2) yp = o2;
  if (pick == 3) yp = o3;
  if (pick == 4) yp = o4;
  y[node] += yp;
}

// ---------------- fused layer GEMM: H[N,128] = A[N,640](bf16) @ W[640,128] + b ----------
// R18: 512 thr = 8 waves; block tile 128 rows x 128 cols (wave w: rows w*16..w*16+15).
// BK=64, 10 k-chunks, LDS As[128][72] + Bs[128][72] (36.9 KB -> 4 blocks/CU max).
// Register prefetch of chunk kc+1 issued after barrier1; 16 MFMAs/wave per stage
// hide it. ReLU epilogue, bf16 out.

__global__ __launch_bounds__(512) void cheb_gemm(
    const unsigned short* __restrict__ T0, const unsigned short* __restrict__ T1,
    const unsigned short* __restrict__ T2, const unsigned short* __restrict__ T3,
    const unsigned short* __restrict__ T4,
    const unsigned short* __restrict__ Wt,
    const float* __restrict__ bias,
    unsigned short* __restrict__ Hb, int M) {
  __shared__ unsigned short As[128][72];  // [row][k 0..63], pad to 72
  __shared__ unsigned short Bs[128][72];  // [col][k 0..63]
  const unsigned short* chunks[5] = {T0, T1, T2, T3, T4};
  int tid = threadIdx.x;
  int wave = tid >> 6, lane = tid & 63;
  int lrow = lane & 15, quad = lane >> 4;
  int rowBase = blockIdx.x * 128;

  f32x4 acc[8];
#pragma unroll
  for (int b = 0; b < 8; ++b) acc[b] = (f32x4){0.f, 0.f, 0.f, 0.f};

  // staging coords: A rows 0..127 (4 thr/row), B cols 0..127 (4 thr/col);
  // each thread stages 2x int4 (16 shorts) for A and for B.
  int ar = tid >> 2, aseg = (tid & 3) * 16;
  int agrow = min(rowBase + ar, M - 1);  // clamp (garbage rows never stored)
  int bc = tid >> 2, bseg = (tid & 3) * 16;

  int4 aR0, aR1, bR0, bR1;
  {
    const unsigned short* ap = chunks[0] + (size_t)agrow * WID + aseg;
    aR0 = *(const int4*)ap;
    aR1 = *(const int4*)(ap + 8);
    const unsigned short* bp = Wt + (size_t)bc * 640 + bseg;
    bR0 = *(const int4*)bp;
    bR1 = *(const int4*)(bp + 8);
  }

  for (int kc = 0; kc < 10; ++kc) {
    *(int4*)(&As[ar][aseg]) = aR0;
    *(int4*)(&As[ar][aseg + 8]) = aR1;
    *(int4*)(&Bs[bc][bseg]) = bR0;
    *(int4*)(&Bs[bc][bseg + 8]) = bR1;
    __syncthreads();

    if (kc < 9) {  // prefetch next chunk; overlaps the 16 MFMAs below
      int kn = kc + 1;
      const unsigned short* ap =
          chunks[kn >> 1] + (size_t)agrow * WID + (kn & 1) * 64 + aseg;
      aR0 = *(const int4*)ap;
      aR1 = *(const int4*)(ap + 8);
      const unsigned short* bp = Wt + (size_t)bc * 640 + kn * 64 + bseg;
      bR0 = *(const int4*)bp;
      bR1 = *(const int4*)(bp + 8);
    }

    bf16x8 a0 = *(bf16x8*)(&As[wave * 16 + lrow][quad * 8]);
    bf16x8 a1 = *(bf16x8*)(&As[wave * 16 + lrow][32 + quad * 8]);
#pragma unroll
    for (int ct = 0; ct < 8; ++ct) {
      bf16x8 b0 = *(bf16x8*)(&Bs[ct * 16 + lrow][quad * 8]);
      acc[ct] = __builtin_amdgcn_mfma_f32_16x16x32_bf16(a0, b0, acc[ct], 0, 0, 0);
      bf16x8 b1 = *(bf16x8*)(&Bs[ct * 16 + lrow][32 + quad * 8]);
      acc[ct] = __builtin_amdgcn_mfma_f32_16x16x32_bf16(a1, b1, acc[ct], 0, 0, 0);
    }
    __syncthreads();
  }

  // epilogue: C/D layout col=lane&15, row=quad*4+reg ; wave rows rowBase+wave*16+...
#pragma unroll
  for (int ct = 0; ct < 8; ++ct) {
    int gcol = ct * 16 + lrow;
    float bv = bias[gcol];
#pragma unroll
    for (int reg = 0; reg < 4; ++reg) {
      int grow = rowBase + wave * 16 + quad * 4 + reg;
      if (grow < M) {
        float v = fmaxf(acc[ct][reg] + bv, 0.f);
        Hb[(size_t)grow * WID + gcol] = f2bf(v);
      }
    }
  }
}

// ---------------- host orchestration ----------------

extern "C" void kernel_launch(void* const* d_in, const int* in_sizes, int n_in,
                              void* d_out, int out_size, void* d_ws, size_t ws_size,
                              hipStream_t stream) {
  const float* x = (const float*)d_in[0];
  const int* ei = (const int*)d_in[1];          // int32 per harness contract
  const float* conv_w = (const float*)d_in[2];  // [6][5][128][128]
  const float* conv_b = (const float*)d_in[3];  // [6][128]
  const float* lin_w = (const float*)d_in[4];   // [128]
  const float* lin_b = (const float*)d_in[5];   // [1]

  const int N = NN, E = NE, C = WID, L = 6;
  const int NB = (N + 255) / 256;

  char* ws = (char*)d_ws;
  size_t off = 0;
  auto alloc = [&](size_t bytes) -> void* {
    void* p = ws + off;
    off = (off + bytes + 255) & ~(size_t)255;
    return p;
  };
  int* deg = (int*)alloc((size_t)N * 4);
  float* dinv = (float*)alloc((size_t)N * 4);
  int* row_start = (int*)alloc((size_t)(N + 1) * 4);
  int* fill_ptr = (int*)alloc((size_t)N * 4);
  int* lex = (int*)alloc((size_t)N * 4);
  int* bsum = (int*)alloc((size_t)NB * 4);
  int* boff = (int*)alloc((size_t)NB * 4);
  unsigned int* csr = (unsigned int*)alloc((size_t)E * 4);
  unsigned short* Xbf = (unsigned short*)alloc((size_t)N * C * 2);
  unsigned short* Hb0 = (unsigned short*)alloc((size_t)N * C * 2);
  unsigned short* Hb1 = (unsigned short*)alloc((size_t)N * C * 2);
  unsigned short* T1b = (unsigned short*)alloc((size_t)N * C * 2);
  unsigned short* T2b = (unsigned short*)alloc((size_t)N * C * 2);
  unsigned short* T3b = (unsigned short*)alloc((size_t)N * C * 2);
  unsigned short* T4b = (unsigned short*)alloc((size_t)N * C * 2);
  unsigned short* Wt = (unsigned short*)alloc((size_t)5 * C * 640 * 2);
  float* V = (float*)alloc((size_t)5 * C * 4);
  float* cst = (float*)alloc(4);

  // preprocessing
  hipMemsetAsync(deg, 0, (size_t)N * 4, stream);
  degree_kernel<<<(E + 255) / 256, 256, 0, stream>>>(ei, deg, E);
  scan1_kernel<<<NB, 256, 0, stream>>>(deg, lex, bsum, dinv, N);
  scan2_kernel<<<1, 256, 0, stream>>>(bsum, boff, &row_start[N], NB);
  scan3_kernel<<<NB, 256, 0, stream>>>(lex, boff, row_start, fill_ptr, N);
  fill_kernel<<<(E + 255) / 256, 256, 0, stream>>>(ei, dinv, fill_ptr, csr, E);
  {
    int nx = N * C, nw = 5 * C * 640;  // layer-5 weights collapse via vk_kernel
    cvt_kernel<<<(nx + nw + 255) / 256, 256, 0, stream>>>(x, Xbf, conv_w, Wt, nx, nw);
  }
  vk_kernel<<<3, 256, 0, stream>>>(conv_w, conv_b, lin_w, lin_b, V, cst);

  const int gg = (N + 127) / 128;  // gemm grid (128 rows/block)

  // layers 0..4: 3 Chebyshev props + Z-prop (W-merged, no sub) + MFMA GEMM + ReLU
  for (int l = 0; l < 5; ++l) {
    const unsigned short* T0 = (l == 0) ? Xbf : ((l & 1) ? Hb0 : Hb1);
    unsigned short* Hb = (l & 1) ? Hb1 : Hb0;

    prop_kernel<<<PROP_BLOCKS, 256, 0, stream>>>(T1b, T0, nullptr, 1.0f, row_start, csr, N);
    prop_kernel<<<PROP_BLOCKS, 256, 0, stream>>>(T2b, T1b, T0, 2.0f, row_start, csr, N);
    prop_kernel<<<PROP_BLOCKS, 256, 0, stream>>>(T3b, T2b, T1b, 2.0f, row_start, csr, N);
    // Z = L*T3 (no sub; weights for chunks 2 and 4 were merged in cvt_kernel)
    prop_kernel<<<PROP_BLOCKS, 256, 0, stream>>>(T4b, T3b, nullptr, 1.0f, row_start, csr, N);
    cheb_gemm<<<gg, 512, 0, stream>>>(T0, T1b, T2b, T3b, T4b,
                                      Wt + (size_t)l * C * 640, conv_b + (size_t)l * C,
                                      Hb, N);
  }

  // final layer (l=5): y = sum_k T_k(L) (H v_k) + cst -- 5-wide fp32 recurrence.
  // H = Hb0 (layer 4 output). Reuse T-buffers as fp32 [N][8] (1.6MB each).
  {
    float* y = (float*)d_out;
    float* U  = (float*)T1b;
    float* P1 = (float*)T2b;
    float* P2 = (float*)T3b;
    float* P3 = (float*)T4b;
    float* P4 = (float*)Xbf;
    const int pg = (N + 255) / 256;
    final_proj<<<(N + 15) / 16, 256, 0, stream>>>(Hb0, V, cst, U, y, N);
    prop_small<<<pg, 256, 0, stream>>>(P1, U, nullptr, 1.0f, 1, y, row_start, csr, N);
    prop_small<<<pg, 256, 0, stream>>>(P2, P1, U, 2.0f, 2, y, row_start, csr, N);
    prop_small<<<pg, 256, 0, stream>>>(P3, P2, P1, 2.0f, 3, y, row_start, csr, N);
    prop_small<<<pg, 256, 0, stream>>>(P4, P3, P2, 2.0f, 4, y, row_start, csr, N);
  }
}